// Round 1
// baseline (477.492 us; speedup 1.0000x reference)
//
#include <hip/hip_runtime.h>
#include <math.h>

#define VOCAB 30000
#define EMB   100
#define HID   128
#define BATCH 1024
#define SEQ   512

// Kernel A: EWx[v][j] = sum_e E[v][e]*Wx[e][j] + b[j]   (folds bias in)
// 30000x128 table, 0.77 GFLOP. Tile: 64 vocab rows x 128 cols per block.
__global__ __launch_bounds__(256) void ewx_kernel(
    const float* __restrict__ E, const float* __restrict__ Wx,
    const float* __restrict__ bias, float* __restrict__ EWx)
{
    __shared__ float Es[64][EMB];     // 25.6 KB
    __shared__ float Wxs[EMB][HID];   // 51.2 KB
    const int tid = threadIdx.x;
    const int v0 = blockIdx.x * 64;
    const int nv = min(64, VOCAB - v0);

    { // load Wx (contiguous, float4)
        const float4* s4 = (const float4*)Wx;
        float4* d4 = (float4*)(&Wxs[0][0]);
        for (int i = tid; i < (EMB * HID) / 4; i += 256) d4[i] = s4[i];
    }
    { // load E tile (contiguous; v0*EMB*4 bytes is 16B-aligned since 400%16==0)
        const float* src = E + (size_t)v0 * EMB;
        float* dst = &Es[0][0];
        const int n  = nv * EMB;
        const int n4 = n >> 2;
        const float4* s4 = (const float4*)src;
        float4* d4 = (float4*)dst;
        for (int i = tid; i < n4; i += 256) d4[i] = s4[i];
        for (int i = (n4 << 2) + tid; i < n; i += 256) dst[i] = src[i];
    }
    __syncthreads();

    const int j  = tid & 127;
    const int vh = tid >> 7;
    float acc[32];
#pragma unroll
    for (int m = 0; m < 32; ++m) acc[m] = 0.f;

    for (int k4 = 0; k4 < EMB; k4 += 4) {   // EMB=100 = 25 * 4, exact
        const float w0 = Wxs[k4 + 0][j];
        const float w1 = Wxs[k4 + 1][j];
        const float w2 = Wxs[k4 + 2][j];
        const float w3 = Wxs[k4 + 3][j];
#pragma unroll
        for (int m = 0; m < 32; ++m) {
            const float4 e = *(const float4*)&Es[vh + 2 * m][k4]; // broadcast
            acc[m] = fmaf(e.x, w0, acc[m]);
            acc[m] = fmaf(e.y, w1, acc[m]);
            acc[m] = fmaf(e.z, w2, acc[m]);
            acc[m] = fmaf(e.w, w3, acc[m]);
        }
    }
    const float bj = bias[j];
#pragma unroll
    for (int m = 0; m < 32; ++m) {
        const int v = vh + 2 * m;
        if (v < nv)
            EWx[(size_t)(v0 + v) * HID + j] = acc[m] + bj;
    }
}

// Kernel B: the sequential recurrence + final sigmoid head.
// 512 blocks x 256 threads; block owns batch rows {2*blk, 2*blk+1}.
// Thread = (j = tid&127, kh = tid>>7). Wh column half lives in 64 VGPRs.
// Per step: h@Wh via LDS broadcast of h, cross-half partial exchange, tanh.
__global__ __launch_bounds__(256) void rnn_kernel(
    const int* __restrict__ X, const float* __restrict__ EWx,
    const float* __restrict__ Wh, const float* __restrict__ Wd,
    const float* __restrict__ bd, float* __restrict__ out)
{
    __shared__ float hbuf[2][2][HID];  // double-buffered h, 2 batch rows
    __shared__ float part[2][HID];     // cross-half partial exchange
    __shared__ int   idx[2][SEQ];      // 4 KB of token indices

    const int tid = threadIdx.x;
    const int j   = tid & 127;
    const int kh  = tid >> 7;          // k-half: 0 or 1
    const int b0  = blockIdx.x * 2;

    // stage this block's token indices
    for (int i = tid; i < 2 * SEQ; i += 256) {
        const int bb = i >> 9;         // / SEQ
        const int tt = i & (SEQ - 1);
        idx[bb][tt] = X[(size_t)(b0 + bb) * SEQ + tt];
    }

    // Wh[kh*64+kk][j] -> registers (coalesced over j)
    float wh[64];
#pragma unroll
    for (int kk = 0; kk < 64; ++kk)
        wh[kk] = Wh[(size_t)(kh * 64 + kk) * HID + j];

    ((float*)hbuf[0])[tid] = 0.f;      // h0 = 0 (256 floats = all of hbuf[0])
    __syncthreads();

    int cur = 0;
    for (int t = 0; t < SEQ; ++t) {
        // issue xp gathers early; consumed after the k-loop (latency hidden)
        const float xp0 = EWx[(size_t)idx[0][t] * HID + j];
        const float xp1 = EWx[(size_t)idx[1][t] * HID + j];

        const float4* h0 = (const float4*)(&hbuf[cur][0][kh * 64]);
        const float4* h1 = (const float4*)(&hbuf[cur][1][kh * 64]);
        float s0e = 0.f, s0o = 0.f, s1e = 0.f, s1o = 0.f; // 4 indep chains
#pragma unroll
        for (int q = 0; q < 16; ++q) {
            const float4 u0 = h0[q];   // ds_read_b128, broadcast
            const float4 u1 = h1[q];
            const float w0 = wh[4*q+0], w1 = wh[4*q+1];
            const float w2 = wh[4*q+2], w3 = wh[4*q+3];
            if (q & 1) {
                s0o = fmaf(u0.x, w0, s0o); s0o = fmaf(u0.y, w1, s0o);
                s0o = fmaf(u0.z, w2, s0o); s0o = fmaf(u0.w, w3, s0o);
                s1o = fmaf(u1.x, w0, s1o); s1o = fmaf(u1.y, w1, s1o);
                s1o = fmaf(u1.z, w2, s1o); s1o = fmaf(u1.w, w3, s1o);
            } else {
                s0e = fmaf(u0.x, w0, s0e); s0e = fmaf(u0.y, w1, s0e);
                s0e = fmaf(u0.z, w2, s0e); s0e = fmaf(u0.w, w3, s0e);
                s1e = fmaf(u1.x, w0, s1e); s1e = fmaf(u1.y, w1, s1e);
                s1e = fmaf(u1.z, w2, s1e); s1e = fmaf(u1.w, w3, s1e);
            }
        }
        const float a0 = s0e + s0o;    // this thread's k-half partial, batch 0
        const float a1 = s1e + s1o;    // batch 1

        // kh=0 finalizes batch 0 (needs kh=1's a0); kh=1 finalizes batch 1
        if (kh == 0) part[1][j] = a1; else part[0][j] = a0;
        __syncthreads();
        if (kh == 0) {
            hbuf[cur ^ 1][0][j] = tanhf(a0 + part[0][j] + xp0);
        } else {
            hbuf[cur ^ 1][1][j] = tanhf(a1 + part[1][j] + xp1);
        }
        __syncthreads();
        cur ^= 1;
    }

    // head: out[b] = sigmoid(h . Wd + bd); wave 0 -> batch 0, wave 1 -> batch 1
    if (tid < 128) {
        const int bb   = tid >> 6;
        const int lane = tid & 63;
        const float* hb = hbuf[cur][bb];
        float v = hb[lane] * Wd[lane] + hb[lane + 64] * Wd[lane + 64];
#pragma unroll
        for (int off = 32; off > 0; off >>= 1)
            v += __shfl_down(v, off, 64);
        if (lane == 0)
            out[b0 + bb] = 1.0f / (1.0f + expf(-(v + bd[0])));
    }
}

extern "C" void kernel_launch(void* const* d_in, const int* in_sizes, int n_in,
                              void* d_out, int out_size, void* d_ws, size_t ws_size,
                              hipStream_t stream)
{
    const int*   X  = (const int*)d_in[0];
    const float* E  = (const float*)d_in[1];
    const float* Wx = (const float*)d_in[2];
    const float* Wh = (const float*)d_in[3];
    const float* b  = (const float*)d_in[4];
    const float* Wd = (const float*)d_in[5];
    const float* bd = (const float*)d_in[6];
    float* out = (float*)d_out;
    float* EWx = (float*)d_ws;   // 30000*128*4 = 15.36 MB scratch

    ewx_kernel<<<dim3((VOCAB + 63) / 64), dim3(256), 0, stream>>>(E, Wx, b, EWx);
    rnn_kernel<<<dim3(BATCH / 2), dim3(256), 0, stream>>>(X, EWx, Wh, Wd, bd, out);
}

// Round 2
// 349.793 us; speedup vs baseline: 1.3651x; 1.3651x over previous
//
#include <hip/hip_runtime.h>
#include <math.h>

#define VOCAB 30000
#define EMB   100
#define HID   128
#define BATCH 1024
#define SEQ   512

// Kernel A: EWx[v][j] = sum_e E[v][e]*Wx[e][j] + b[j]   (folds bias in)
__global__ __launch_bounds__(256) void ewx_kernel(
    const float* __restrict__ E, const float* __restrict__ Wx,
    const float* __restrict__ bias, float* __restrict__ EWx)
{
    __shared__ float Es[64][EMB];     // 25.6 KB
    __shared__ float Wxs[EMB][HID];   // 51.2 KB
    const int tid = threadIdx.x;
    const int v0 = blockIdx.x * 64;
    const int nv = min(64, VOCAB - v0);

    {
        const float4* s4 = (const float4*)Wx;
        float4* d4 = (float4*)(&Wxs[0][0]);
        for (int i = tid; i < (EMB * HID) / 4; i += 256) d4[i] = s4[i];
    }
    {
        const float* src = E + (size_t)v0 * EMB;
        float* dst = &Es[0][0];
        const int n  = nv * EMB;
        const int n4 = n >> 2;
        const float4* s4 = (const float4*)src;
        float4* d4 = (float4*)dst;
        for (int i = tid; i < n4; i += 256) d4[i] = s4[i];
        for (int i = (n4 << 2) + tid; i < n; i += 256) dst[i] = src[i];
    }
    __syncthreads();

    const int j  = tid & 127;
    const int vh = tid >> 7;
    float acc[32];
#pragma unroll
    for (int m = 0; m < 32; ++m) acc[m] = 0.f;

    for (int k4 = 0; k4 < EMB; k4 += 4) {
        const float w0 = Wxs[k4 + 0][j];
        const float w1 = Wxs[k4 + 1][j];
        const float w2 = Wxs[k4 + 2][j];
        const float w3 = Wxs[k4 + 3][j];
#pragma unroll
        for (int m = 0; m < 32; ++m) {
            const float4 e = *(const float4*)&Es[vh + 2 * m][k4];
            acc[m] = fmaf(e.x, w0, acc[m]);
            acc[m] = fmaf(e.y, w1, acc[m]);
            acc[m] = fmaf(e.z, w2, acc[m]);
            acc[m] = fmaf(e.w, w3, acc[m]);
        }
    }
    const float bj = bias[j];
#pragma unroll
    for (int m = 0; m < 32; ++m) {
        const int v = vh + 2 * m;
        if (v < nv)
            EWx[(size_t)(v0 + v) * HID + j] = acc[m] + bj;
    }
}

// Kernel B: sequential recurrence, G=4 column-blocking.
// Block = 256 threads, 2 batch rows. Thread = (rr = tid>>7, kq = (tid>>5)&3,
// jg = tid&31): owns Wh[kq*32 .. +31][jg + 32*{0..3}] in 128 VGPRs.
// Per step: read 32 h values (8 x ds_read_b128, broadcast) -> 128 FMAs into
// 4 accs -> 4-way cross-kq reduce through LDS -> tanh -> write h_new.
// LDS traffic per FMA drops 4x vs one-column-per-thread.
__global__ __launch_bounds__(256, 2) void rnn_kernel(
    const int* __restrict__ X, const float* __restrict__ EWx,
    const float* __restrict__ Wh, const float* __restrict__ Wd,
    const float* __restrict__ bd, float* __restrict__ out)
{
    __shared__ float hbuf[2][2][HID];  // double-buffered h, 2 batch rows
    __shared__ float part[2][4][HID];  // per-kq partial sums
    __shared__ int   idx[2][SEQ];      // token indices

    const int tid = threadIdx.x;
    const int rr  = tid >> 7;          // batch row within block (0/1)
    const int kq  = (tid >> 5) & 3;    // k-quarter (0..3)
    const int jg  = tid & 31;          // column group lane
    const int b0  = blockIdx.x * 2;

    for (int i = tid; i < 2 * SEQ; i += 256) {
        const int bb = i >> 9;
        const int tt = i & (SEQ - 1);
        idx[bb][tt] = X[(size_t)(b0 + bb) * SEQ + tt];
    }

    // Wh slice -> registers: wh[kk*4+c] = Wh[kq*32+kk][jg+32c]
    float wh[128];
#pragma unroll
    for (int kk = 0; kk < 32; ++kk) {
#pragma unroll
        for (int c = 0; c < 4; ++c)
            wh[kk * 4 + c] = Wh[(size_t)(kq * 32 + kk) * HID + jg + 32 * c];
    }

    ((float*)hbuf[0])[tid] = 0.f;      // h0 = 0 (256 floats)
    const int jf = kq * 32 + jg;       // the one column this thread finalizes
    __syncthreads();

    int cur = 0;
    for (int t = 0; t < SEQ; ++t) {
        // prefetch xp for the finalize phase (hidden under the k-loop)
        const int   tok = idx[rr][t];
        const float xp  = EWx[(size_t)tok * HID + jf];

        const float4* h4 = (const float4*)(&hbuf[cur][rr][kq * 32]);
        float a0 = 0.f, a1 = 0.f, a2 = 0.f, a3 = 0.f;
#pragma unroll
        for (int q = 0; q < 8; ++q) {
            const float4 u = h4[q];    // broadcast ds_read_b128
#pragma unroll
            for (int m = 0; m < 4; ++m) {
                const float hv = (m == 0) ? u.x : (m == 1) ? u.y : (m == 2) ? u.z : u.w;
                const int kk = 4 * q + m;
                a0 = fmaf(hv, wh[kk * 4 + 0], a0);
                a1 = fmaf(hv, wh[kk * 4 + 1], a1);
                a2 = fmaf(hv, wh[kk * 4 + 2], a2);
                a3 = fmaf(hv, wh[kk * 4 + 3], a3);
            }
        }
        // partials for columns jg+32c over k-range [kq*32, kq*32+32)
        part[rr][kq][jg +  0] = a0;
        part[rr][kq][jg + 32] = a1;
        part[rr][kq][jg + 64] = a2;
        part[rr][kq][jg + 96] = a3;
        __syncthreads();

        // finalize column jf of row rr: 4-way reduce + xp, branchless tanh
        const float s = part[rr][0][jf] + part[rr][1][jf]
                      + part[rr][2][jf] + part[rr][3][jf] + xp;
        const float x  = fminf(fmaxf(s, -9.f), 9.f);   // tanh saturates past 9
        const float e2 = __expf(2.f * x);
        hbuf[cur ^ 1][rr][jf] = __fdividef(e2 - 1.f, e2 + 1.f);
        __syncthreads();
        cur ^= 1;
    }

    // head: out[b] = sigmoid(h . Wd + bd)
    if (tid < 128) {
        const int bb   = tid >> 6;
        const int lane = tid & 63;
        const float* hb = hbuf[cur][bb];
        float v = hb[lane] * Wd[lane] + hb[lane + 64] * Wd[lane + 64];
#pragma unroll
        for (int off = 32; off > 0; off >>= 1)
            v += __shfl_down(v, off, 64);
        if (lane == 0)
            out[b0 + bb] = 1.0f / (1.0f + expf(-(v + bd[0])));
    }
}

extern "C" void kernel_launch(void* const* d_in, const int* in_sizes, int n_in,
                              void* d_out, int out_size, void* d_ws, size_t ws_size,
                              hipStream_t stream)
{
    const int*   X  = (const int*)d_in[0];
    const float* E  = (const float*)d_in[1];
    const float* Wx = (const float*)d_in[2];
    const float* Wh = (const float*)d_in[3];
    const float* b  = (const float*)d_in[4];
    const float* Wd = (const float*)d_in[5];
    const float* bd = (const float*)d_in[6];
    float* out = (float*)d_out;
    float* EWx = (float*)d_ws;   // 30000*128*4 = 15.36 MB scratch

    ewx_kernel<<<dim3((VOCAB + 63) / 64), dim3(256), 0, stream>>>(E, Wx, b, EWx);
    rnn_kernel<<<dim3(BATCH / 2), dim3(256), 0, stream>>>(X, EWx, Wh, Wd, bd, out);
}